// Round 1
// baseline (3640.767 us; speedup 1.0000x reference)
//
#include <hip/hip_runtime.h>
#include <hip/hip_bf16.h>
#include <math.h>

#define BS 8192
#define DH 1024
#define DE 256
#define NL 64

__device__ __forceinline__ float dot4(float4 a, float4 b){
  return fmaf(a.x,b.x, fmaf(a.y,b.y, fmaf(a.z,b.z, a.w*b.w)));
}

// ---------------- label histogram + stable group scatter (1 block) ----------------
__global__ void hist_groups_kernel(const int* __restrict__ labels, int* __restrict__ cnt,
    int* __restrict__ offs, int* __restrict__ groups){
  __shared__ unsigned short loc[256][64];   // per-thread-chunk per-label counts
  __shared__ int off_s[65];
  __shared__ int cnt_s[64];
  int t = threadIdx.x;
  #pragma unroll
  for (int l=0;l<64;l++) loc[t][l]=0;
  __syncthreads();
  int base = t * 32;                        // 8192/256 = 32 per thread
  for (int i=0;i<32;i++){
    int y = labels[base+i];
    loc[t][y] = (unsigned short)(loc[t][y] + 1);
  }
  __syncthreads();
  if (t < 64){                              // exclusive scan over threads per label
    int run = 0;
    for (int tt=0;tt<256;tt++){
      int v = loc[tt][t];
      loc[tt][t] = (unsigned short)run;
      run += v;
    }
    cnt_s[t] = run;
    cnt[t] = run;
  }
  __syncthreads();
  if (t == 0){
    int acc = 0;
    for (int l=0;l<64;l++){ off_s[l] = acc; acc += cnt_s[l]; }
    off_s[64] = acc;
  }
  __syncthreads();
  if (t < 65) offs[t] = off_s[t];
  for (int i=0;i<32;i++){                   // stable deterministic scatter
    int idx = base + i;
    int y = labels[idx];
    int p = off_s[y] + loc[t][y];
    loc[t][y] = (unsigned short)(loc[t][y] + 1);
    groups[p] = idx;
  }
}

// ---------------- normalize label prototypes (1 block) ----------------
__global__ void labelnorm_kernel(const float* __restrict__ label_emb, float* __restrict__ ln){
  __shared__ float red[256];
  int t = threadIdx.x;
  for (int r=0;r<NL;r++){
    float v = label_emb[r*DE + t];
    red[t] = v*v;
    __syncthreads();
    for (int s=128;s>0;s>>=1){
      if (t<s) red[t] += red[t+s];
      __syncthreads();
    }
    float inv = 1.0f / fmaxf(sqrtf(red[0]), 1e-8f);
    ln[r*DE + t] = v * inv;
    __syncthreads();
  }
}

// ---------------- emb = mask @ W^T + b, row-normalized -> en ----------------
// block = 32 rows x 256 cols; thread = 4 rows x 8 cols. No LDS staging:
// mask reads are wave-broadcast (same addr across col-group lanes), W rows L1-resident.
__global__ __launch_bounds__(256) void emb_kernel(const float* __restrict__ mask,
    const float* __restrict__ W, const float* __restrict__ bias, float* __restrict__ en){
  int t = threadIdx.x;
  int cg = t & 31;                // cols cg*8 .. +7
  int rg = t >> 5;                // rows rg*4 .. +3
  int rb = blockIdx.x * 32;
  const float* mbase = mask + (size_t)(rb + rg*4) * DH;
  const float* wbase = W + (size_t)(cg*8) * DH;
  float acc[4][8];
  #pragma unroll
  for (int i=0;i<4;i++)
    #pragma unroll
    for (int j=0;j<8;j++) acc[i][j]=0.f;
  for (int k=0;k<DH;k+=4){
    float4 mv[4];
    float4 wv[8];
    #pragma unroll
    for (int i=0;i<4;i++) mv[i] = *(const float4*)(mbase + i*DH + k);
    #pragma unroll
    for (int j=0;j<8;j++) wv[j] = *(const float4*)(wbase + j*DH + k);
    #pragma unroll
    for (int i=0;i<4;i++)
      #pragma unroll
      for (int j=0;j<8;j++) acc[i][j] += dot4(mv[i], wv[j]);
  }
  __shared__ float red[32*32];
  __shared__ float inv_s[32];
  #pragma unroll
  for (int i=0;i<4;i++){
    float s = 0.f;
    #pragma unroll
    for (int j=0;j<8;j++){ float v = acc[i][j] + bias[cg*8+j]; acc[i][j] = v; s += v*v; }
    red[(rg*4+i)*32 + cg] = s;
  }
  __syncthreads();
  if (t < 32){
    float s = 0.f;
    #pragma unroll
    for (int c=0;c<32;c++) s += red[t*32+c];
    inv_s[t] = 1.0f / fmaxf(sqrtf(s), 1e-8f);
  }
  __syncthreads();
  #pragma unroll
  for (int i=0;i<4;i++){
    float iv = inv_s[rg*4+i];
    float* dst = en + (size_t)(rb+rg*4+i)*DE + cg*8;
    float4 o0 = make_float4(acc[i][0]*iv, acc[i][1]*iv, acc[i][2]*iv, acc[i][3]*iv);
    float4 o1 = make_float4(acc[i][4]*iv, acc[i][5]*iv, acc[i][6]*iv, acc[i][7]*iv);
    *(float4*)dst = o0;
    *(float4*)(dst+4) = o1;
  }
}

// ---------------- N[i] partials: sum over diff-label cols of exp(en_i . en_j) ----------------
// grid (128 row-tiles, 8 col-splits); block tile 64 rows x 1024 cols, inner 64-col subtiles,
// thread tile 4x4. Reads from global (L1/L2-resident en), no big LDS.
__global__ __launch_bounds__(256) void npass_kernel(const float* __restrict__ en,
    const int* __restrict__ labels, float* __restrict__ N_part){
  int t = threadIdx.x;
  int tr = t >> 4, tc = t & 15;
  int rb = blockIdx.x * 64;
  int cb = blockIdx.y * 1024;
  int ylab[4];
  #pragma unroll
  for (int i=0;i<4;i++) ylab[i] = labels[rb + tr*4 + i];
  const float* rp = en + (size_t)(rb + tr*4) * DE;
  float Nacc[4] = {0.f,0.f,0.f,0.f};
  for (int sub=0; sub<16; sub++){
    int cbase = cb + sub*64 + tc*4;
    int clab[4];
    #pragma unroll
    for (int j=0;j<4;j++) clab[j] = labels[cbase + j];
    const float* cp = en + (size_t)cbase * DE;
    float acc[4][4];
    #pragma unroll
    for (int i=0;i<4;i++)
      #pragma unroll
      for (int j=0;j<4;j++) acc[i][j]=0.f;
    #pragma unroll 2
    for (int kk=0; kk<DE; kk+=4){
      float4 rv[4], cv[4];
      #pragma unroll
      for (int i=0;i<4;i++) rv[i] = *(const float4*)(rp + i*DE + kk);
      #pragma unroll
      for (int j=0;j<4;j++) cv[j] = *(const float4*)(cp + j*DE + kk);
      #pragma unroll
      for (int i=0;i<4;i++)
        #pragma unroll
        for (int j=0;j<4;j++) acc[i][j] += dot4(rv[i], cv[j]);
    }
    #pragma unroll
    for (int i=0;i<4;i++)
      #pragma unroll
      for (int j=0;j<4;j++)
        if (clab[j] != ylab[i]) Nacc[i] += __expf(acc[i][j]);
  }
  __shared__ float red[16][64];
  #pragma unroll
  for (int i=0;i<4;i++) red[tc][tr*4+i] = Nacc[i];
  __syncthreads();
  if (t < 64){
    float s = 0.f;
    #pragma unroll
    for (int c=0;c<16;c++) s += red[c][t];
    N_part[(size_t)blockIdx.y*BS + rb + t] = s;
  }
}

// ---------------- C = en . ln^T : expCT (transposed), pos, row exp-sum ----------------
// 4 rows/block; one wave per row, lane = label.
__global__ __launch_bounds__(256) void c_kernel(const float* __restrict__ en,
    const float* __restrict__ ln, const int* __restrict__ labels,
    float* __restrict__ expCT, float* __restrict__ pos, float* __restrict__ rowsum){
  int t = threadIdx.x;
  int r = blockIdx.x*4 + (t>>6);
  int l = t & 63;
  const float* er = en + (size_t)r*DE;
  const float* lr = ln + (size_t)l*DE;
  float s = 0.f;
  #pragma unroll 4
  for (int k=0;k<DE;k+=4){
    float4 a = *(const float4*)(er+k);
    float4 b = *(const float4*)(lr+k);
    s += dot4(a,b);
  }
  float e = __expf(s);
  expCT[(size_t)l*BS + r] = e;
  float tot = e;
  #pragma unroll
  for (int o=32;o>0;o>>=1) tot += __shfl_down(tot, o);
  int y = labels[r];
  if (l == 0) rowsum[r] = tot;
  if (l == y) pos[r] = s;
}

// ---------------- per-label T[l] = sum_j exp(C[j,l]); G[l] = same-label subset ----------------
__global__ void tg_kernel(const float* __restrict__ expCT, const int* __restrict__ labels,
    float* __restrict__ Tl, float* __restrict__ Gl){
  int l = blockIdx.x; int t = threadIdx.x;
  const float* col = expCT + (size_t)l*BS;
  float ts=0.f, gs=0.f;
  for (int i=t;i<BS;i+=256){
    float v = col[i];
    ts += v;
    if (labels[i]==l) gs += v;
  }
  __shared__ float rt_[256], rg_[256];
  rt_[t]=ts; rg_[t]=gs; __syncthreads();
  for (int s=128;s>0;s>>=1){ if (t<s){ rt_[t]+=rt_[t+s]; rg_[t]+=rg_[t+s]; } __syncthreads(); }
  if (t==0){ Tl[l]=rt_[0]; Gl[l]=rg_[0]; }
}

__global__ void reduceN_kernel(const float* __restrict__ N_part, float* __restrict__ Nrow){
  int i = blockIdx.x*256 + threadIdx.x;
  float s = 0.f;
  #pragma unroll
  for (int c=0;c<8;c++) s += N_part[(size_t)c*BS + i];
  Nrow[i] = s;
}

// ---------------- same-label ordered pairs: sum(-S + log(N[i]+exp(S))) ----------------
__global__ __launch_bounds__(256) void pairs_kernel(const float* __restrict__ en,
    const int* __restrict__ cnt, const int* __restrict__ offs,
    const int* __restrict__ groups, const float* __restrict__ Nrow,
    float* __restrict__ pairp){
  int l = blockIdx.x;
  int m = cnt[l];
  int off = offs[l];
  int t = threadIdx.x;
  int ty = t >> 4, tx = t & 15;
  int nt = (m + 15) >> 4;
  float sum = 0.f;
  for (int ta=0; ta<nt; ta++){
    int a = ta*16 + ty;
    for (int tb=0; tb<nt; tb++){
      int b = tb*16 + tx;
      if (a < m && b < m && a != b){
        int ia = groups[off+a];
        int ib = groups[off+b];
        const float* ra = en + (size_t)ia*DE;
        const float* rb2 = en + (size_t)ib*DE;
        float s = 0.f;
        #pragma unroll 4
        for (int k=0;k<DE;k+=4){
          float4 va = *(const float4*)(ra+k);
          float4 vb = *(const float4*)(rb2+k);
          s += dot4(va,vb);
        }
        sum += -s + __logf(Nrow[ia] + __expf(s));
      }
    }
  }
  __shared__ float red[256];
  red[t] = sum;
  __syncthreads();
  for (int s=128;s>0;s>>=1){ if (t<s) red[t]+=red[t+s]; __syncthreads(); }
  if (t==0) pairp[l] = red[0];
}

// ---------------- final scalar assembly (1 block, f64 accumulation) ----------------
__global__ void finalize_kernel(const int* __restrict__ labels, const int* __restrict__ cnt,
    const float* __restrict__ Nrow, const float* __restrict__ pos,
    const float* __restrict__ rowsum, const float* __restrict__ Tl,
    const float* __restrict__ Gl, const float* __restrict__ expCT,
    const float* __restrict__ pairp, float* __restrict__ out){
  __shared__ double red[3*256];
  int t = threadIdx.x;
  double a=0.0, p1=0.0, p2=0.0;
  for (int i=t; i<BS; i+=256){
    int y = labels[i];
    double Ni = (double)Nrow[i];
    a += (double)(BS - cnt[y]) * log(Ni + 1.0);
    double ps = (double)pos[i];
    p1 += -ps + log((double)rowsum[i]);                       // neg1 + exp(pos) = full row sum
    double neg2 = (double)Tl[y] - (double)Gl[y];
    p2 += -ps + log(neg2 + (double)expCT[(size_t)y*BS + i]);  // expCT[y][i] == exp(pos[i])
  }
  red[t]=a; red[256+t]=p1; red[512+t]=p2;
  __syncthreads();
  for (int s=128;s>0;s>>=1){
    if (t<s){ red[t]+=red[t+s]; red[256+t]+=red[256+t+s]; red[512+t]+=red[512+t+s]; }
    __syncthreads();
  }
  if (t==0){
    double pair = 0.0;
    for (int l=0;l<64;l++) pair += (double)pairp[l];
    double inter = (red[0] + pair) / ((double)BS * (double)BS);
    double proto = (red[256] + red[512]) / (double)BS;
    out[0] = (float)(0.5*inter + 0.5*proto);
  }
}

extern "C" void kernel_launch(void* const* d_in, const int* in_sizes, int n_in,
                              void* d_out, int out_size, void* d_ws, size_t ws_size,
                              hipStream_t stream){
  const float* mask  = (const float*)d_in[0];
  const float* W     = (const float*)d_in[1];
  const float* bias  = (const float*)d_in[2];
  const float* lemb  = (const float*)d_in[3];
  const int*   labels= (const int*)d_in[4];
  float* out = (float*)d_out;

  // workspace layout (~11 MB)
  float* en     = (float*)d_ws;                 // 8192*256
  float* ln     = en + (size_t)BS*DE;           // 64*256
  float* expCT  = ln + (size_t)NL*DE;           // 64*8192
  float* N_part = expCT + (size_t)NL*BS;        // 8*8192
  float* Nrow   = N_part + (size_t)8*BS;        // 8192
  float* pos    = Nrow + BS;                    // 8192
  float* rowsum = pos + BS;                     // 8192
  float* Tl     = rowsum + BS;                  // 64
  float* Gl     = Tl + NL;                      // 64
  float* pairp  = Gl + NL;                      // 64
  int* cnt    = (int*)(pairp + NL);             // 64
  int* offs   = cnt + NL;                       // 65 (padded to 68)
  int* groups = offs + 68;                      // 8192

  hipLaunchKernelGGL(hist_groups_kernel, dim3(1), dim3(256), 0, stream, labels, cnt, offs, groups);
  hipLaunchKernelGGL(labelnorm_kernel,   dim3(1), dim3(256), 0, stream, lemb, ln);
  hipLaunchKernelGGL(emb_kernel,         dim3(BS/32), dim3(256), 0, stream, mask, W, bias, en);
  hipLaunchKernelGGL(npass_kernel,       dim3(BS/64, 8), dim3(256), 0, stream, en, labels, N_part);
  hipLaunchKernelGGL(c_kernel,           dim3(BS/4), dim3(256), 0, stream, en, ln, labels, expCT, pos, rowsum);
  hipLaunchKernelGGL(tg_kernel,          dim3(NL), dim3(256), 0, stream, expCT, labels, Tl, Gl);
  hipLaunchKernelGGL(reduceN_kernel,     dim3(BS/256), dim3(256), 0, stream, N_part, Nrow);
  hipLaunchKernelGGL(pairs_kernel,       dim3(NL), dim3(256), 0, stream, en, cnt, offs, groups, Nrow, pairp);
  hipLaunchKernelGGL(finalize_kernel,    dim3(1), dim3(256), 0, stream, labels, cnt, Nrow, pos, rowsum, Tl, Gl, expCT, pairp, out);
}

// Round 2
// 503.423 us; speedup vs baseline: 7.2320x; 7.2320x over previous
//
#include <hip/hip_runtime.h>
#include <hip/hip_bf16.h>
#include <math.h>

#define BS 8192
#define DH 1024
#define DE 256
#define NL 64

typedef __attribute__((ext_vector_type(8))) short short8;
typedef __attribute__((ext_vector_type(4))) float f32x4;
typedef unsigned short ushort;

__device__ __forceinline__ float dot4(float4 a, float4 b){
  return fmaf(a.x,b.x, fmaf(a.y,b.y, fmaf(a.z,b.z, a.w*b.w)));
}

__device__ __forceinline__ ushort bf16b(float f){
  unsigned u = __float_as_uint(f);
  unsigned r = (u + 0x7FFFu + ((u >> 16) & 1u)) >> 16;
  return (ushort)r;
}

__device__ __forceinline__ void gload_lds16(const void* g, void* l){
  __builtin_amdgcn_global_load_lds((const __attribute__((address_space(1))) void*)g,
                                   (__attribute__((address_space(3))) void*)l, 16, 0, 0);
}

// ---------------- W f32 -> bf16 ----------------
__global__ __launch_bounds__(256) void wcvt_kernel(const float* __restrict__ W, ushort* __restrict__ Wb){
  int i = (blockIdx.x*256 + threadIdx.x) * 8;
  float4 v0 = *(const float4*)(W+i);
  float4 v1 = *(const float4*)(W+i+4);
  short8 o;
  o[0]=bf16b(v0.x); o[1]=bf16b(v0.y); o[2]=bf16b(v0.z); o[3]=bf16b(v0.w);
  o[4]=bf16b(v1.x); o[5]=bf16b(v1.y); o[6]=bf16b(v1.z); o[7]=bf16b(v1.w);
  *(short8*)(Wb+i) = o;
}

// ---------------- label histogram + stable group scatter (1 block) ----------------
__global__ void hist_groups_kernel(const int* __restrict__ labels, int* __restrict__ cnt,
    int* __restrict__ offs, int* __restrict__ groups){
  __shared__ ushort loc[256][64];
  __shared__ int off_s[65];
  __shared__ int cnt_s[64];
  int t = threadIdx.x;
  #pragma unroll
  for (int l=0;l<64;l++) loc[t][l]=0;
  __syncthreads();
  int base = t * 32;
  for (int i=0;i<32;i++){
    int y = labels[base+i];
    loc[t][y] = (ushort)(loc[t][y] + 1);
  }
  __syncthreads();
  if (t < 64){
    int run = 0;
    for (int tt=0;tt<256;tt++){
      int v = loc[tt][t];
      loc[tt][t] = (ushort)run;
      run += v;
    }
    cnt_s[t] = run;
    cnt[t] = run;
  }
  __syncthreads();
  if (t == 0){
    int acc = 0;
    for (int l=0;l<64;l++){ off_s[l] = acc; acc += cnt_s[l]; }
    off_s[64] = acc;
  }
  __syncthreads();
  if (t < 65) offs[t] = off_s[t];
  for (int i=0;i<32;i++){
    int idx = base + i;
    int y = labels[idx];
    int p = off_s[y] + loc[t][y];
    loc[t][y] = (ushort)(loc[t][y] + 1);
    groups[p] = idx;
  }
}

// ---------------- normalize label prototypes (64 blocks) ----------------
__global__ __launch_bounds__(256) void labelnorm_kernel(const float* __restrict__ label_emb, float* __restrict__ ln){
  __shared__ float red[256];
  int l = blockIdx.x, t = threadIdx.x;
  float v = label_emb[l*DE + t];
  red[t] = v*v;
  __syncthreads();
  for (int s=128;s>0;s>>=1){
    if (t<s) red[t] += red[t+s];
    __syncthreads();
  }
  float inv = 1.0f / fmaxf(sqrtf(red[0]), 1e-8f);
  ln[l*DE + t] = v * inv;
}

// ---------------- emb = mask @ W^T + b, row-norm; MFMA bf16 ----------------
// BM=64 rows, BN=256 (full E), BK=64, K=1024. 4 waves; wave w -> cols w*64..+63.
__global__ __launch_bounds__(256) void emb_kernel(const float* __restrict__ mask,
    const ushort* __restrict__ Wb, const float* __restrict__ bias,
    float* __restrict__ en, ushort* __restrict__ enb){
  __shared__ ushort Ab[64*64];    // 8KB  swizzled [row][chunk^(row&7)]
  __shared__ ushort Bb[256*64];   // 32KB swizzled
  __shared__ float sq[4][64];
  __shared__ float inv_s[64];
  int tid = threadIdx.x, lane = tid & 63, w = tid >> 6;
  int rb = blockIdx.x * 64;
  f32x4 acc[4][4] = {};
  for (int kb = 0; kb < DH; kb += 64){
    #pragma unroll
    for (int q=0;q<2;q++){          // A: f32 -> bf16 reg staging, 512 slots
      int s = q*256 + tid;
      int row = s >> 3, cc = s & 7;
      int lc = cc ^ (row & 7);
      const float* g = mask + (size_t)(rb+row)*DH + kb + lc*8;
      float4 v0 = *(const float4*)g;
      float4 v1 = *(const float4*)(g+4);
      short8 o;
      o[0]=bf16b(v0.x); o[1]=bf16b(v0.y); o[2]=bf16b(v0.z); o[3]=bf16b(v0.w);
      o[4]=bf16b(v1.x); o[5]=bf16b(v1.y); o[6]=bf16b(v1.z); o[7]=bf16b(v1.w);
      *(short8*)&Ab[s*8] = o;
    }
    #pragma unroll
    for (int q=0;q<8;q++){          // B: global_load_lds, 2048 slots
      int chunk = q*4 + w;
      int lin = chunk*64 + lane;
      int row = lin >> 3, cc = lin & 7;
      int lc = cc ^ (row & 7);
      gload_lds16(Wb + (size_t)row*DH + kb + lc*8, &Bb[(size_t)chunk*64*8]);
    }
    __syncthreads();
    #pragma unroll
    for (int kk=0;kk<2;kk++){
      short8 af[4], bfr[4];
      #pragma unroll
      for (int m=0;m<4;m++){
        int row = m*16 + (lane & 15);
        int phys = (kk*4 + (lane >> 4)) ^ (row & 7);
        af[m] = *(const short8*)&Ab[row*64 + phys*8];
      }
      #pragma unroll
      for (int n=0;n<4;n++){
        int row = w*64 + n*16 + (lane & 15);
        int phys = (kk*4 + (lane >> 4)) ^ (row & 7);
        bfr[n] = *(const short8*)&Bb[row*64 + phys*8];
      }
      #pragma unroll
      for (int m=0;m<4;m++)
        #pragma unroll
        for (int n=0;n<4;n++)
          acc[m][n] = __builtin_amdgcn_mfma_f32_16x16x32_bf16(af[m], bfr[n], acc[m][n], 0,0,0);
    }
    __syncthreads();
  }
  // epilogue: +bias, row sumsq, normalize, write f32 + bf16
  int qr = lane >> 4, c15 = lane & 15;
  float bv[4];
  #pragma unroll
  for (int n=0;n<4;n++) bv[n] = bias[w*64 + n*16 + c15];
  #pragma unroll
  for (int m=0;m<4;m++){
    #pragma unroll
    for (int r=0;r<4;r++){
      float s = 0.f;
      #pragma unroll
      for (int n=0;n<4;n++){
        float v = acc[m][n][r] + bv[n];
        acc[m][n][r] = v;
        s += v*v;
      }
      #pragma unroll
      for (int msk=8; msk>=1; msk>>=1) s += __shfl_xor(s, msk);
      if (c15 == 0) sq[w][m*16 + qr*4 + r] = s;
    }
  }
  __syncthreads();
  if (tid < 64){
    float s = sq[0][tid] + sq[1][tid] + sq[2][tid] + sq[3][tid];
    inv_s[tid] = 1.0f / fmaxf(sqrtf(s), 1e-8f);
  }
  __syncthreads();
  #pragma unroll
  for (int m=0;m<4;m++){
    #pragma unroll
    for (int r=0;r<4;r++){
      int row = m*16 + qr*4 + r;
      float iv = inv_s[row];
      #pragma unroll
      for (int n=0;n<4;n++){
        int col = w*64 + n*16 + c15;
        float v = acc[m][n][r] * iv;
        en [(size_t)(rb+row)*DE + col] = v;
        enb[(size_t)(rb+row)*DE + col] = bf16b(v);
      }
    }
  }
}

// ---------------- N pass: fused S=en.en^T MFMA + exp + mask + row-reduce ----------------
// 128x128 tile, BK=64, K=256. 4 waves 2x2, each 64x64.
__global__ __launch_bounds__(256) void npass_kernel(const ushort* __restrict__ enb,
    const int* __restrict__ labels, float* __restrict__ N_part){
  __shared__ ushort Ab[128*64];   // 16KB swizzled
  __shared__ ushort Bb[128*64];   // 16KB
  __shared__ float nred[2][128];
  int tid = threadIdx.x, lane = tid & 63, w = tid >> 6;
  int wr = w >> 1, wc = w & 1;
  int rb = blockIdx.x * 128;
  int cb = blockIdx.y * 128;
  f32x4 acc[4][4] = {};
  for (int kb = 0; kb < DE; kb += 64){
    #pragma unroll
    for (int q=0;q<4;q++){
      int chunk = q*4 + w;
      int lin = chunk*64 + lane;
      int row = lin >> 3, cc = lin & 7;
      int lc = cc ^ (row & 7);
      gload_lds16(enb + (size_t)(rb + row)*DE + kb + lc*8, &Ab[(size_t)chunk*64*8]);
      gload_lds16(enb + (size_t)(cb + row)*DE + kb + lc*8, &Bb[(size_t)chunk*64*8]);
    }
    __syncthreads();
    #pragma unroll
    for (int kk=0;kk<2;kk++){
      short8 af[4], bfr[4];
      #pragma unroll
      for (int m=0;m<4;m++){
        int row = wr*64 + m*16 + (lane & 15);
        int phys = (kk*4 + (lane >> 4)) ^ (row & 7);
        af[m] = *(const short8*)&Ab[row*64 + phys*8];
      }
      #pragma unroll
      for (int n=0;n<4;n++){
        int row = wc*64 + n*16 + (lane & 15);
        int phys = (kk*4 + (lane >> 4)) ^ (row & 7);
        bfr[n] = *(const short8*)&Bb[row*64 + phys*8];
      }
      #pragma unroll
      for (int m=0;m<4;m++)
        #pragma unroll
        for (int n=0;n<4;n++)
          acc[m][n] = __builtin_amdgcn_mfma_f32_16x16x32_bf16(af[m], bfr[n], acc[m][n], 0,0,0);
    }
    __syncthreads();
  }
  // epilogue: mask + exp + row-sum
  int qr = lane >> 4, c15 = lane & 15;
  int cl[4];
  #pragma unroll
  for (int n=0;n<4;n++) cl[n] = labels[cb + wc*64 + n*16 + c15];
  #pragma unroll
  for (int m=0;m<4;m++){
    #pragma unroll
    for (int r=0;r<4;r++){
      int rlab = labels[rb + wr*64 + m*16 + qr*4 + r];
      float s = 0.f;
      #pragma unroll
      for (int n=0;n<4;n++){
        float v = acc[m][n][r];
        if (cl[n] != rlab) s += __expf(v);
      }
      #pragma unroll
      for (int msk=8; msk>=1; msk>>=1) s += __shfl_xor(s, msk);
      if (c15 == 0) nred[wc][wr*64 + m*16 + qr*4 + r] = s;
    }
  }
  __syncthreads();
  if (tid < 128)
    N_part[(size_t)blockIdx.y * BS + rb + tid] = nred[0][tid] + nred[1][tid];
}

// ---------------- C = en . ln^T ----------------
__global__ __launch_bounds__(256) void c_kernel(const float* __restrict__ en,
    const float* __restrict__ ln, const int* __restrict__ labels,
    float* __restrict__ expCT, float* __restrict__ pos, float* __restrict__ rowsum){
  int t = threadIdx.x;
  int r = blockIdx.x*4 + (t>>6);
  int l = t & 63;
  const float* er = en + (size_t)r*DE;
  const float* lr = ln + (size_t)l*DE;
  float s = 0.f;
  #pragma unroll 4
  for (int k=0;k<DE;k+=4){
    float4 a = *(const float4*)(er+k);
    float4 b = *(const float4*)(lr+k);
    s += dot4(a,b);
  }
  float e = __expf(s);
  expCT[(size_t)l*BS + r] = e;
  float tot = e;
  #pragma unroll
  for (int o=32;o>0;o>>=1) tot += __shfl_down(tot, o);
  int y = labels[r];
  if (l == 0) rowsum[r] = tot;
  if (l == y) pos[r] = s;
}

// ---------------- per-label T/G column sums ----------------
__global__ void tg_kernel(const float* __restrict__ expCT, const int* __restrict__ labels,
    float* __restrict__ Tl, float* __restrict__ Gl){
  int l = blockIdx.x; int t = threadIdx.x;
  const float* col = expCT + (size_t)l*BS;
  float ts=0.f, gs=0.f;
  for (int i=t;i<BS;i+=256){
    float v = col[i];
    ts += v;
    if (labels[i]==l) gs += v;
  }
  __shared__ float rt_[256], rg_[256];
  rt_[t]=ts; rg_[t]=gs; __syncthreads();
  for (int s=128;s>0;s>>=1){ if (t<s){ rt_[t]+=rt_[t+s]; rg_[t]+=rg_[t+s]; } __syncthreads(); }
  if (t==0){ Tl[l]=rt_[0]; Gl[l]=rg_[0]; }
}

__global__ void reduceN_kernel(const float* __restrict__ N_part, float* __restrict__ Nrow){
  int i = blockIdx.x*256 + threadIdx.x;
  float s = 0.f;
  #pragma unroll
  for (int c=0;c<64;c++) s += N_part[(size_t)c*BS + i];
  Nrow[i] = s;
}

// ---------------- same-label ordered pairs (grid 64 x 8 splits) ----------------
__global__ __launch_bounds__(256) void pairs_kernel(const float* __restrict__ en,
    const int* __restrict__ cnt, const int* __restrict__ offs,
    const int* __restrict__ groups, const float* __restrict__ Nrow,
    float* __restrict__ pairp){
  int l = blockIdx.x;
  int split = blockIdx.y;
  int m = cnt[l];
  int off = offs[l];
  int t = threadIdx.x;
  int ty = t >> 4, tx = t & 15;
  int nt = (m + 15) >> 4;
  float sum = 0.f;
  for (int ta=split; ta<nt; ta+=8){
    int a = ta*16 + ty;
    for (int tb=0; tb<nt; tb++){
      int b = tb*16 + tx;
      if (a < m && b < m && a != b){
        int ia = groups[off+a];
        int ib = groups[off+b];
        const float* ra = en + (size_t)ia*DE;
        const float* rb2 = en + (size_t)ib*DE;
        float s = 0.f;
        #pragma unroll 4
        for (int k=0;k<DE;k+=4){
          float4 va = *(const float4*)(ra+k);
          float4 vb = *(const float4*)(rb2+k);
          s += dot4(va,vb);
        }
        sum += -s + __logf(Nrow[ia] + __expf(s));
      }
    }
  }
  __shared__ float red[256];
  red[t] = sum;
  __syncthreads();
  for (int s=128;s>0;s>>=1){ if (t<s) red[t]+=red[t+s]; __syncthreads(); }
  if (t==0) pairp[split*64 + l] = red[0];
}

// ---------------- final scalar assembly ----------------
__global__ void finalize_kernel(const int* __restrict__ labels, const int* __restrict__ cnt,
    const float* __restrict__ Nrow, const float* __restrict__ pos,
    const float* __restrict__ rowsum, const float* __restrict__ Tl,
    const float* __restrict__ Gl, const float* __restrict__ expCT,
    const float* __restrict__ pairp, float* __restrict__ out){
  __shared__ double red[3*256];
  int t = threadIdx.x;
  double a=0.0, p1=0.0, p2=0.0;
  for (int i=t; i<BS; i+=256){
    int y = labels[i];
    double Ni = (double)Nrow[i];
    a += (double)(BS - cnt[y]) * log(Ni + 1.0);
    double ps = (double)pos[i];
    p1 += -ps + log((double)rowsum[i]);
    double neg2 = (double)Tl[y] - (double)Gl[y];
    p2 += -ps + log(neg2 + (double)expCT[(size_t)y*BS + i]);
  }
  red[t]=a; red[256+t]=p1; red[512+t]=p2;
  __syncthreads();
  for (int s=128;s>0;s>>=1){
    if (t<s){ red[t]+=red[t+s]; red[256+t]+=red[256+t+s]; red[512+t]+=red[512+t+s]; }
    __syncthreads();
  }
  if (t==0){
    double pair = 0.0;
    for (int l=0;l<512;l++) pair += (double)pairp[l];
    double inter = (red[0] + pair) / ((double)BS * (double)BS);
    double proto = (red[256] + red[512]) / (double)BS;
    out[0] = (float)(0.5*inter + 0.5*proto);
  }
}

extern "C" void kernel_launch(void* const* d_in, const int* in_sizes, int n_in,
                              void* d_out, int out_size, void* d_ws, size_t ws_size,
                              hipStream_t stream){
  const float* mask  = (const float*)d_in[0];
  const float* W     = (const float*)d_in[1];
  const float* bias  = (const float*)d_in[2];
  const float* lemb  = (const float*)d_in[3];
  const int*   labels= (const int*)d_in[4];
  float* out = (float*)d_out;

  // workspace layout (~17 MB)
  float*  en     = (float*)d_ws;                    // 8192*256 f32
  ushort* enb    = (ushort*)(en + (size_t)BS*DE);   // 8192*256 bf16
  ushort* Wb     = enb + (size_t)BS*DE;             // 256*1024 bf16
  float*  ln     = (float*)(Wb + (size_t)DE*DH);    // 64*256
  float*  expCT  = ln + (size_t)NL*DE;              // 64*8192
  float*  N_part = expCT + (size_t)NL*BS;           // 64*8192
  float*  Nrow   = N_part + (size_t)64*BS;          // 8192
  float*  pos    = Nrow + BS;                       // 8192
  float*  rowsum = pos + BS;                        // 8192
  float*  Tl     = rowsum + BS;                     // 64
  float*  Gl     = Tl + NL;                         // 64
  float*  pairp  = Gl + NL;                         // 512
  int* cnt    = (int*)(pairp + 512);                // 64
  int* offs   = cnt + NL;                           // 65 (pad 68)
  int* groups = offs + 68;                          // 8192

  hipLaunchKernelGGL(wcvt_kernel,        dim3(DE*DH/(256*8)), dim3(256), 0, stream, W, Wb);
  hipLaunchKernelGGL(labelnorm_kernel,   dim3(NL), dim3(256), 0, stream, lemb, ln);
  hipLaunchKernelGGL(hist_groups_kernel, dim3(1), dim3(256), 0, stream, labels, cnt, offs, groups);
  hipLaunchKernelGGL(emb_kernel,         dim3(BS/64), dim3(256), 0, stream, mask, Wb, bias, en, enb);
  hipLaunchKernelGGL(npass_kernel,       dim3(BS/128, BS/128), dim3(256), 0, stream, enb, labels, N_part);
  hipLaunchKernelGGL(c_kernel,           dim3(BS/4), dim3(256), 0, stream, en, ln, labels, expCT, pos, rowsum);
  hipLaunchKernelGGL(tg_kernel,          dim3(NL), dim3(256), 0, stream, expCT, labels, Tl, Gl);
  hipLaunchKernelGGL(reduceN_kernel,     dim3(BS/256), dim3(256), 0, stream, N_part, Nrow);
  hipLaunchKernelGGL(pairs_kernel,       dim3(NL, 8), dim3(256), 0, stream, en, cnt, offs, groups, Nrow, pairp);
  hipLaunchKernelGGL(finalize_kernel,    dim3(1), dim3(256), 0, stream, labels, cnt, Nrow, pos, rowsum, Tl, Gl, expCT, pairp, out);
}

// Round 3
// 183.487 us; speedup vs baseline: 19.8421x; 2.7437x over previous
//
#include <hip/hip_runtime.h>
#include <hip/hip_bf16.h>
#include <math.h>

#define BS 8192
#define DH 1024
#define DE 256
#define NL 64

typedef __attribute__((ext_vector_type(8))) short short8;
typedef __attribute__((ext_vector_type(4))) float f32x4;
typedef unsigned short ushort;

__device__ __forceinline__ ushort bf16b(float f){
  unsigned u = __float_as_uint(f);
  unsigned r = (u + 0x7FFFu + ((u >> 16) & 1u)) >> 16;
  return (ushort)r;
}

__device__ __forceinline__ void gload_lds16(const void* g, void* l){
  __builtin_amdgcn_global_load_lds((const __attribute__((address_space(1))) void*)g,
                                   (__attribute__((address_space(3))) void*)l, 16, 0, 0);
}

// ---------------- W f32 -> bf16 ----------------
__global__ __launch_bounds__(256) void wcvt_kernel(const float* __restrict__ W, ushort* __restrict__ Wb){
  int i = (blockIdx.x*256 + threadIdx.x) * 8;
  float4 v0 = *(const float4*)(W+i);
  float4 v1 = *(const float4*)(W+i+4);
  short8 o;
  o[0]=bf16b(v0.x); o[1]=bf16b(v0.y); o[2]=bf16b(v0.z); o[3]=bf16b(v0.w);
  o[4]=bf16b(v1.x); o[5]=bf16b(v1.y); o[6]=bf16b(v1.z); o[7]=bf16b(v1.w);
  *(short8*)(Wb+i) = o;
}

// ---------------- label histogram + stable group scatter (1 block) ----------------
__global__ void hist_groups_kernel(const int* __restrict__ labels, int* __restrict__ cnt,
    int* __restrict__ offs, int* __restrict__ groups){
  __shared__ ushort loc[256][64];
  __shared__ int off_s[65];
  __shared__ int cnt_s[64];
  int t = threadIdx.x;
  #pragma unroll
  for (int l=0;l<64;l++) loc[t][l]=0;
  __syncthreads();
  int base = t * 32;
  for (int i=0;i<32;i++){
    int y = labels[base+i];
    loc[t][y] = (ushort)(loc[t][y] + 1);
  }
  __syncthreads();
  if (t < 64){
    int run = 0;
    for (int tt=0;tt<256;tt++){
      int v = loc[tt][t];
      loc[tt][t] = (ushort)run;
      run += v;
    }
    cnt_s[t] = run;
    cnt[t] = run;
  }
  __syncthreads();
  if (t == 0){
    int acc = 0;
    for (int l=0;l<64;l++){ off_s[l] = acc; acc += cnt_s[l]; }
    off_s[64] = acc;
  }
  __syncthreads();
  if (t < 65) offs[t] = off_s[t];
  for (int i=0;i<32;i++){
    int idx = base + i;
    int y = labels[idx];
    int p = off_s[y] + loc[t][y];
    loc[t][y] = (ushort)(loc[t][y] + 1);
    groups[p] = idx;
  }
}

// ---------------- normalize label prototypes -> bf16 (64 blocks) ----------------
__global__ __launch_bounds__(256) void labelnorm_kernel(const float* __restrict__ label_emb, ushort* __restrict__ lnb){
  __shared__ float red[256];
  int l = blockIdx.x, t = threadIdx.x;
  float v = label_emb[l*DE + t];
  red[t] = v*v;
  __syncthreads();
  for (int s=128;s>0;s>>=1){
    if (t<s) red[t] += red[t+s];
    __syncthreads();
  }
  float inv = 1.0f / fmaxf(sqrtf(red[0]), 1e-8f);
  lnb[l*DE + t] = bf16b(v * inv);
}

// ---------------- emb = mask @ W^T + b, row-norm; MFMA bf16 -> enb ----------------
__global__ __launch_bounds__(256) void emb_kernel(const float* __restrict__ mask,
    const ushort* __restrict__ Wb, const float* __restrict__ bias,
    ushort* __restrict__ enb){
  __shared__ ushort Ab[64*64];
  __shared__ ushort Bb[256*64];
  __shared__ float sq[4][64];
  __shared__ float inv_s[64];
  int tid = threadIdx.x, lane = tid & 63, w = tid >> 6;
  int rb = blockIdx.x * 64;
  f32x4 acc[4][4] = {};
  for (int kb = 0; kb < DH; kb += 64){
    #pragma unroll
    for (int q=0;q<2;q++){          // A: f32 -> bf16 reg staging
      int s = q*256 + tid;
      int row = s >> 3, cc = s & 7;
      int lc = cc ^ (row & 7);
      const float* g = mask + (size_t)(rb+row)*DH + kb + lc*8;
      float4 v0 = *(const float4*)g;
      float4 v1 = *(const float4*)(g+4);
      short8 o;
      o[0]=bf16b(v0.x); o[1]=bf16b(v0.y); o[2]=bf16b(v0.z); o[3]=bf16b(v0.w);
      o[4]=bf16b(v1.x); o[5]=bf16b(v1.y); o[6]=bf16b(v1.z); o[7]=bf16b(v1.w);
      *(short8*)&Ab[s*8] = o;
    }
    #pragma unroll
    for (int q=0;q<8;q++){          // B: global_load_lds
      int chunk = q*4 + w;
      int lin = chunk*64 + lane;
      int row = lin >> 3, cc = lin & 7;
      int lc = cc ^ (row & 7);
      gload_lds16(Wb + (size_t)row*DH + kb + lc*8, &Bb[(size_t)chunk*64*8]);
    }
    __syncthreads();
    #pragma unroll
    for (int kk=0;kk<2;kk++){
      short8 af[4], bfr[4];
      #pragma unroll
      for (int m=0;m<4;m++){
        int row = m*16 + (lane & 15);
        int phys = (kk*4 + (lane >> 4)) ^ (row & 7);
        af[m] = *(const short8*)&Ab[row*64 + phys*8];
      }
      #pragma unroll
      for (int n=0;n<4;n++){
        int row = w*64 + n*16 + (lane & 15);
        int phys = (kk*4 + (lane >> 4)) ^ (row & 7);
        bfr[n] = *(const short8*)&Bb[row*64 + phys*8];
      }
      #pragma unroll
      for (int m=0;m<4;m++)
        #pragma unroll
        for (int n=0;n<4;n++)
          acc[m][n] = __builtin_amdgcn_mfma_f32_16x16x32_bf16(af[m], bfr[n], acc[m][n], 0,0,0);
    }
    __syncthreads();
  }
  int qr = lane >> 4, c15 = lane & 15;
  float bv[4];
  #pragma unroll
  for (int n=0;n<4;n++) bv[n] = bias[w*64 + n*16 + c15];
  #pragma unroll
  for (int m=0;m<4;m++){
    #pragma unroll
    for (int r=0;r<4;r++){
      float s = 0.f;
      #pragma unroll
      for (int n=0;n<4;n++){
        float v = acc[m][n][r] + bv[n];
        acc[m][n][r] = v;
        s += v*v;
      }
      #pragma unroll
      for (int msk=8; msk>=1; msk>>=1) s += __shfl_xor(s, msk);
      if (c15 == 0) sq[w][m*16 + qr*4 + r] = s;
    }
  }
  __syncthreads();
  if (tid < 64){
    float s = sq[0][tid] + sq[1][tid] + sq[2][tid] + sq[3][tid];
    inv_s[tid] = 1.0f / fmaxf(sqrtf(s), 1e-8f);
  }
  __syncthreads();
  #pragma unroll
  for (int m=0;m<4;m++){
    #pragma unroll
    for (int r=0;r<4;r++){
      int row = m*16 + qr*4 + r;
      float iv = inv_s[row];
      #pragma unroll
      for (int n=0;n<4;n++){
        int col = w*64 + n*16 + c15;
        enb[(size_t)(rb+row)*DE + col] = bf16b(acc[m][n][r] * iv);
      }
    }
  }
}

// ---------------- N pass: fused S=en.en^T MFMA + exp + mask + row-reduce ----------------
__global__ __launch_bounds__(256) void npass_kernel(const ushort* __restrict__ enb,
    const int* __restrict__ labels, float* __restrict__ N_part){
  __shared__ ushort Ab[128*64];
  __shared__ ushort Bb[128*64];
  __shared__ float nred[2][128];
  int tid = threadIdx.x, lane = tid & 63, w = tid >> 6;
  int wr = w >> 1, wc = w & 1;
  int rb = blockIdx.x * 128;
  int cb = blockIdx.y * 128;
  f32x4 acc[4][4] = {};
  for (int kb = 0; kb < DE; kb += 64){
    #pragma unroll
    for (int q=0;q<4;q++){
      int chunk = q*4 + w;
      int lin = chunk*64 + lane;
      int row = lin >> 3, cc = lin & 7;
      int lc = cc ^ (row & 7);
      gload_lds16(enb + (size_t)(rb + row)*DE + kb + lc*8, &Ab[(size_t)chunk*64*8]);
      gload_lds16(enb + (size_t)(cb + row)*DE + kb + lc*8, &Bb[(size_t)chunk*64*8]);
    }
    __syncthreads();
    #pragma unroll
    for (int kk=0;kk<2;kk++){
      short8 af[4], bfr[4];
      #pragma unroll
      for (int m=0;m<4;m++){
        int row = wr*64 + m*16 + (lane & 15);
        int phys = (kk*4 + (lane >> 4)) ^ (row & 7);
        af[m] = *(const short8*)&Ab[row*64 + phys*8];
      }
      #pragma unroll
      for (int n=0;n<4;n++){
        int row = wc*64 + n*16 + (lane & 15);
        int phys = (kk*4 + (lane >> 4)) ^ (row & 7);
        bfr[n] = *(const short8*)&Bb[row*64 + phys*8];
      }
      #pragma unroll
      for (int m=0;m<4;m++)
        #pragma unroll
        for (int n=0;n<4;n++)
          acc[m][n] = __builtin_amdgcn_mfma_f32_16x16x32_bf16(af[m], bfr[n], acc[m][n], 0,0,0);
    }
    __syncthreads();
  }
  int qr = lane >> 4, c15 = lane & 15;
  int cl[4];
  #pragma unroll
  for (int n=0;n<4;n++) cl[n] = labels[cb + wc*64 + n*16 + c15];
  #pragma unroll
  for (int m=0;m<4;m++){
    #pragma unroll
    for (int r=0;r<4;r++){
      int rlab = labels[rb + wr*64 + m*16 + qr*4 + r];
      float s = 0.f;
      #pragma unroll
      for (int n=0;n<4;n++){
        float v = acc[m][n][r];
        if (cl[n] != rlab) s += __expf(v);
      }
      #pragma unroll
      for (int msk=8; msk>=1; msk>>=1) s += __shfl_xor(s, msk);
      if (c15 == 0) nred[wc][wr*64 + m*16 + qr*4 + r] = s;
    }
  }
  __syncthreads();
  if (tid < 128)
    N_part[(size_t)blockIdx.y * BS + rb + tid] = nred[0][tid] + nred[1][tid];
}

// ---------------- fused C-pass: pos, rowsum, T/G column partials (MFMA) ----------------
__global__ __launch_bounds__(256) void c2_kernel(const ushort* __restrict__ enb,
    const ushort* __restrict__ lnb, const int* __restrict__ labels,
    float* __restrict__ pos, float* __restrict__ rowsum,
    float* __restrict__ T_part, float* __restrict__ G_part){
  __shared__ ushort Ab[64*64];
  __shared__ ushort Bb[64*64];
  __shared__ float TpS[4][64];
  __shared__ float GpS[4][64];
  int tid = threadIdx.x, lane = tid & 63, w = tid >> 6;
  int qr = lane >> 4, c15 = lane & 15;
  int rb = blockIdx.x * 64;
  f32x4 acc[4] = {};
  for (int kb = 0; kb < DE; kb += 64){
    #pragma unroll
    for (int q=0;q<2;q++){
      int chunk = q*4 + w;
      int lin = chunk*64 + lane;
      int row = lin >> 3, cc = lin & 7;
      int lc = cc ^ (row & 7);
      gload_lds16(enb + (size_t)(rb+row)*DE + kb + lc*8, &Ab[(size_t)chunk*64*8]);
    }
    #pragma unroll
    for (int q=0;q<2;q++){
      int chunk = q*4 + w;
      int lin = chunk*64 + lane;
      int row = lin >> 3, cc = lin & 7;
      int lc = cc ^ (row & 7);
      gload_lds16(lnb + (size_t)row*DE + kb + lc*8, &Bb[(size_t)chunk*64*8]);
    }
    __syncthreads();
    #pragma unroll
    for (int kk=0;kk<2;kk++){
      int arow = w*16 + (lane & 15);
      int aphys = (kk*4 + (lane >> 4)) ^ (arow & 7);
      short8 af = *(const short8*)&Ab[arow*64 + aphys*8];
      #pragma unroll
      for (int ni=0;ni<4;ni++){
        int brow = ni*16 + (lane & 15);
        int bphys = (kk*4 + (lane >> 4)) ^ (brow & 7);
        short8 bfr = *(const short8*)&Bb[brow*64 + bphys*8];
        acc[ni] = __builtin_amdgcn_mfma_f32_16x16x32_bf16(af, bfr, acc[ni], 0,0,0);
      }
    }
    __syncthreads();
  }
  int yr[4];
  #pragma unroll
  for (int r=0;r<4;r++) yr[r] = labels[rb + w*16 + qr*4 + r];
  float e[4][4];
  #pragma unroll
  for (int ni=0;ni<4;ni++)
    #pragma unroll
    for (int r=0;r<4;r++) e[ni][r] = __expf(acc[ni][r]);
  #pragma unroll
  for (int r=0;r<4;r++){
    float rs = e[0][r]+e[1][r]+e[2][r]+e[3][r];
    float ps = 0.f;
    #pragma unroll
    for (int ni=0;ni<4;ni++) if (ni*16 + c15 == yr[r]) ps = acc[ni][r];
    #pragma unroll
    for (int msk=8; msk>=1; msk>>=1){ rs += __shfl_xor(rs, msk); ps += __shfl_xor(ps, msk); }
    if (c15 == 0){
      int grow = rb + w*16 + qr*4 + r;
      rowsum[grow] = rs;
      pos[grow] = ps;
    }
  }
  #pragma unroll
  for (int ni=0;ni<4;ni++){
    int col = ni*16 + c15;
    float t = 0.f, g = 0.f;
    #pragma unroll
    for (int r=0;r<4;r++){
      t += e[ni][r];
      if (col == yr[r]) g += e[ni][r];
    }
    t += __shfl_xor(t, 16); t += __shfl_xor(t, 32);
    g += __shfl_xor(g, 16); g += __shfl_xor(g, 32);
    if (qr == 0){ TpS[w][col] = t; GpS[w][col] = g; }
  }
  __syncthreads();
  if (tid < 64){
    T_part[(size_t)blockIdx.x*64 + tid] = TpS[0][tid]+TpS[1][tid]+TpS[2][tid]+TpS[3][tid];
    G_part[(size_t)blockIdx.x*64 + tid] = GpS[0][tid]+GpS[1][tid]+GpS[2][tid]+GpS[3][tid];
  }
}

__global__ void reduceN_kernel(const float* __restrict__ N_part, float* __restrict__ Nrow){
  int i = blockIdx.x*256 + threadIdx.x;
  float s = 0.f;
  #pragma unroll
  for (int c=0;c<64;c++) s += N_part[(size_t)c*BS + i];
  Nrow[i] = s;
}

// ---------------- same-label pairs via gathered MFMA group-GEMM ----------------
// grid (64 labels, 4 row-tiles); block: 64 gathered rows x 256 gathered cols, K=256.
__global__ __launch_bounds__(256) void pairs_kernel(const ushort* __restrict__ enb,
    const int* __restrict__ cnt, const int* __restrict__ offs,
    const int* __restrict__ groups, const float* __restrict__ Nrow,
    float* __restrict__ pairp){
  __shared__ ushort Ab[64*64];
  __shared__ ushort Bb[256*64];
  __shared__ int aidx[64];
  __shared__ int gidx[256];
  __shared__ float red[256];
  int l = blockIdx.x, rt = blockIdx.y;
  int m = cnt[l], off = offs[l];
  int tid = threadIdx.x, lane = tid & 63, w = tid >> 6;
  int qr = lane >> 4, c15 = lane & 15;
  float sum = 0.f;
  for (int ra = rt*64; ra < m; ra += 256){
    __syncthreads();
    if (tid < 64){ int a = ra + tid; aidx[tid] = groups[off + (a < m ? a : 0)]; }
    for (int cb2 = 0; cb2 < m; cb2 += 256){
      __syncthreads();
      { int b = cb2 + tid; gidx[tid] = groups[off + (b < m ? b : 0)]; }
      __syncthreads();
      f32x4 acc[4][4] = {};
      for (int kb = 0; kb < DE; kb += 64){
        #pragma unroll
        for (int q=0;q<2;q++){
          int chunk = q*4 + w;
          int lin = chunk*64 + lane;
          int row = lin >> 3, cc = lin & 7;
          int lc = cc ^ (row & 7);
          gload_lds16(enb + (size_t)aidx[row]*DE + kb + lc*8, &Ab[(size_t)chunk*64*8]);
        }
        #pragma unroll
        for (int q=0;q<8;q++){
          int chunk = q*4 + w;
          int lin = chunk*64 + lane;
          int row = lin >> 3, cc = lin & 7;
          int lc = cc ^ (row & 7);
          gload_lds16(enb + (size_t)gidx[row]*DE + kb + lc*8, &Bb[(size_t)chunk*64*8]);
        }
        __syncthreads();
        #pragma unroll
        for (int kk=0;kk<2;kk++){
          short8 af[4], bfr[4];
          #pragma unroll
          for (int mi=0;mi<4;mi++){
            int row = mi*16 + (lane & 15);
            int phys = (kk*4 + (lane >> 4)) ^ (row & 7);
            af[mi] = *(const short8*)&Ab[row*64 + phys*8];
          }
          #pragma unroll
          for (int ni=0;ni<4;ni++){
            int row = w*64 + ni*16 + (lane & 15);
            int phys = (kk*4 + (lane >> 4)) ^ (row & 7);
            bfr[ni] = *(const short8*)&Bb[row*64 + phys*8];
          }
          #pragma unroll
          for (int mi=0;mi<4;mi++)
            #pragma unroll
            for (int ni=0;ni<4;ni++)
              acc[mi][ni] = __builtin_amdgcn_mfma_f32_16x16x32_bf16(af[mi], bfr[ni], acc[mi][ni], 0,0,0);
        }
        __syncthreads();
      }
      #pragma unroll
      for (int mi=0;mi<4;mi++){
        #pragma unroll
        for (int r=0;r<4;r++){
          int arel = mi*16 + qr*4 + r;
          int a = ra + arel;
          if (a < m){
            float Ni = Nrow[aidx[arel]];
            #pragma unroll
            for (int ni=0;ni<4;ni++){
              int b = cb2 + w*64 + ni*16 + c15;
              if (b < m && b != a){
                float s = acc[mi][ni][r];
                sum += -s + __logf(Ni + __expf(s));
              }
            }
          }
        }
      }
    }
  }
  red[tid] = sum;
  __syncthreads();
  for (int s=128;s>0;s>>=1){ if (tid<s) red[tid]+=red[tid+s]; __syncthreads(); }
  if (tid==0) pairp[l*4 + rt] = red[0];
}

// ---------------- final scalar assembly ----------------
__global__ void finalize_kernel(const int* __restrict__ labels, const int* __restrict__ cnt,
    const float* __restrict__ Nrow, const float* __restrict__ pos,
    const float* __restrict__ rowsum, const float* __restrict__ T_part,
    const float* __restrict__ G_part, const float* __restrict__ pairp,
    float* __restrict__ out){
  __shared__ double red[3*256];
  __shared__ double TlS[64], GlS[64];
  int t = threadIdx.x;
  if (t < 64){
    double ts = 0.0, gs = 0.0;
    for (int b=0;b<128;b++){ ts += (double)T_part[b*64 + t]; gs += (double)G_part[b*64 + t]; }
    TlS[t] = ts; GlS[t] = gs;
  }
  __syncthreads();
  double a=0.0, p1=0.0, p2=0.0;
  for (int i=t; i<BS; i+=256){
    int y = labels[i];
    double Ni = (double)Nrow[i];
    a += (double)(BS - cnt[y]) * log(Ni + 1.0);
    double ps = (double)pos[i];
    p1 += -ps + log((double)rowsum[i]);
    p2 += -ps + log(TlS[y] - GlS[y] + exp(ps));
  }
  red[t]=a; red[256+t]=p1; red[512+t]=p2;
  __syncthreads();
  for (int s=128;s>0;s>>=1){
    if (t<s){ red[t]+=red[t+s]; red[256+t]+=red[256+t+s]; red[512+t]+=red[512+t+s]; }
    __syncthreads();
  }
  if (t==0){
    double pair = 0.0;
    for (int l=0;l<256;l++) pair += (double)pairp[l];
    double inter = (red[0] + pair) / ((double)BS * (double)BS);
    double proto = (red[256] + red[512]) / (double)BS;
    out[0] = (float)(0.5*inter + 0.5*proto);
  }
}

extern "C" void kernel_launch(void* const* d_in, const int* in_sizes, int n_in,
                              void* d_out, int out_size, void* d_ws, size_t ws_size,
                              hipStream_t stream){
  const float* mask  = (const float*)d_in[0];
  const float* W     = (const float*)d_in[1];
  const float* bias  = (const float*)d_in[2];
  const float* lemb  = (const float*)d_in[3];
  const int*   labels= (const int*)d_in[4];
  float* out = (float*)d_out;

  // workspace layout (~7 MB)
  ushort* enb    = (ushort*)d_ws;                   // 8192*256 bf16 (4MB)
  ushort* Wb     = enb + (size_t)BS*DE;             // 256*1024 bf16 (512KB)
  ushort* lnb    = Wb + (size_t)DE*DH;              // 64*256 bf16 (32KB)
  float*  N_part = (float*)(lnb + (size_t)NL*DE);   // 64*8192 (2MB)
  float*  Nrow   = N_part + (size_t)64*BS;          // 8192
  float*  pos    = Nrow + BS;                       // 8192
  float*  rowsum = pos + BS;                        // 8192
  float*  T_part = rowsum + BS;                     // 128*64
  float*  G_part = T_part + 128*64;                 // 128*64
  float*  pairp  = G_part + 128*64;                 // 256
  int* cnt    = (int*)(pairp + 256);                // 64
  int* offs   = cnt + NL;                           // 65 (pad 68)
  int* groups = offs + 68;                          // 8192

  hipLaunchKernelGGL(wcvt_kernel,        dim3(DE*DH/(256*8)), dim3(256), 0, stream, W, Wb);
  hipLaunchKernelGGL(labelnorm_kernel,   dim3(NL), dim3(256), 0, stream, lemb, lnb);
  hipLaunchKernelGGL(hist_groups_kernel, dim3(1), dim3(256), 0, stream, labels, cnt, offs, groups);
  hipLaunchKernelGGL(emb_kernel,         dim3(BS/64), dim3(256), 0, stream, mask, Wb, bias, enb);
  hipLaunchKernelGGL(npass_kernel,       dim3(BS/128, BS/128), dim3(256), 0, stream, enb, labels, N_part);
  hipLaunchKernelGGL(c2_kernel,          dim3(BS/64), dim3(256), 0, stream, enb, lnb, labels, pos, rowsum, T_part, G_part);
  hipLaunchKernelGGL(reduceN_kernel,     dim3(BS/256), dim3(256), 0, stream, N_part, Nrow);
  hipLaunchKernelGGL(pairs_kernel,       dim3(NL, 4), dim3(256), 0, stream, enb, cnt, offs, groups, Nrow, pairp);
  hipLaunchKernelGGL(finalize_kernel,    dim3(1), dim3(256), 0, stream, labels, cnt, Nrow, pos, rowsum, T_part, G_part, pairp, out);
}

// Round 4
// 149.954 us; speedup vs baseline: 24.2793x; 1.2236x over previous
//
#include <hip/hip_runtime.h>
#include <hip/hip_bf16.h>
#include <math.h>

#define BS 8192
#define DH 1024
#define DE 256
#define NL 64

typedef __attribute__((ext_vector_type(8))) short short8;
typedef __attribute__((ext_vector_type(4))) float f32x4;
typedef unsigned short ushort;

__device__ __forceinline__ ushort bf16b(float f){
  unsigned u = __float_as_uint(f);
  unsigned r = (u + 0x7FFFu + ((u >> 16) & 1u)) >> 16;
  return (ushort)r;
}

__device__ __forceinline__ void gload_lds16(const void* g, void* l){
  __builtin_amdgcn_global_load_lds((const __attribute__((address_space(1))) void*)g,
                                   (__attribute__((address_space(3))) void*)l, 16, 0, 0);
}

// ---------------- fused prep: wcvt (b<128) | labelnorm (128<=b<192) | hist (b==192) ----------------
__global__ __launch_bounds__(256) void prep_kernel(const float* __restrict__ W, ushort* __restrict__ Wb,
    const float* __restrict__ label_emb, ushort* __restrict__ lnb,
    const int* __restrict__ labels, int* __restrict__ cnt,
    int* __restrict__ offs, int* __restrict__ groups){
  int b = blockIdx.x, t = threadIdx.x;
  if (b < 128){                        // W f32 -> bf16
    int i = (b*256 + t) * 8;
    float4 v0 = *(const float4*)(W+i);
    float4 v1 = *(const float4*)(W+i+4);
    short8 o;
    o[0]=bf16b(v0.x); o[1]=bf16b(v0.y); o[2]=bf16b(v0.z); o[3]=bf16b(v0.w);
    o[4]=bf16b(v1.x); o[5]=bf16b(v1.y); o[6]=bf16b(v1.z); o[7]=bf16b(v1.w);
    *(short8*)(Wb+i) = o;
    return;
  }
  if (b < 192){                        // label prototype normalize -> bf16
    __shared__ float red[256];
    int l = b - 128;
    float v = label_emb[l*DE + t];
    red[t] = v*v;
    __syncthreads();
    for (int s=128;s>0;s>>=1){
      if (t<s) red[t] += red[t+s];
      __syncthreads();
    }
    float inv = 1.0f / fmaxf(sqrtf(red[0]), 1e-8f);
    lnb[l*DE + t] = bf16b(v * inv);
    return;
  }
  // b == 192: histogram + stable group scatter
  __shared__ ushort loc[256][64];
  __shared__ int off_s[65];
  __shared__ int cnt_s[64];
  #pragma unroll
  for (int l=0;l<64;l++) loc[t][l]=0;
  __syncthreads();
  int base = t * 32;
  for (int i=0;i<32;i++){
    int y = labels[base+i];
    loc[t][y] = (ushort)(loc[t][y] + 1);
  }
  __syncthreads();
  if (t < 64){
    int run = 0;
    for (int tt=0;tt<256;tt++){
      int v = loc[tt][t];
      loc[tt][t] = (ushort)run;
      run += v;
    }
    cnt_s[t] = run;
    cnt[t] = run;
  }
  __syncthreads();
  if (t == 0){
    int acc = 0;
    for (int l=0;l<64;l++){ off_s[l] = acc; acc += cnt_s[l]; }
    off_s[64] = acc;
  }
  __syncthreads();
  if (t < 65) offs[t] = off_s[t];
  for (int i=0;i<32;i++){
    int idx = base + i;
    int y = labels[idx];
    int p = off_s[y] + loc[t][y];
    loc[t][y] = (ushort)(loc[t][y] + 1);
    groups[p] = idx;
  }
}

// ---------------- emb = mask @ W^T + b, row-norm; MFMA bf16 -> enb (BM=32, grid 256) ----------------
__global__ __launch_bounds__(256) void emb_kernel(const float* __restrict__ mask,
    const ushort* __restrict__ Wb, const float* __restrict__ bias,
    ushort* __restrict__ enb){
  __shared__ ushort Ab[32*64];    // 4KB
  __shared__ ushort Bb[256*64];   // 32KB
  __shared__ float sq[4][32];
  __shared__ float inv_s[32];
  int tid = threadIdx.x, lane = tid & 63, w = tid >> 6;
  int rb = blockIdx.x * 32;
  f32x4 acc[2][4] = {};
  for (int kb = 0; kb < DH; kb += 64){
    {                               // A: f32 -> bf16 reg staging (256 slots)
      int s = tid;
      int row = s >> 3, cc = s & 7;
      int lc = cc ^ (row & 7);
      const float* g = mask + (size_t)(rb+row)*DH + kb + lc*8;
      float4 v0 = *(const float4*)g;
      float4 v1 = *(const float4*)(g+4);
      short8 o;
      o[0]=bf16b(v0.x); o[1]=bf16b(v0.y); o[2]=bf16b(v0.z); o[3]=bf16b(v0.w);
      o[4]=bf16b(v1.x); o[5]=bf16b(v1.y); o[6]=bf16b(v1.z); o[7]=bf16b(v1.w);
      *(short8*)&Ab[s*8] = o;
    }
    #pragma unroll
    for (int q=0;q<8;q++){          // B: global_load_lds
      int chunk = q*4 + w;
      int lin = chunk*64 + lane;
      int row = lin >> 3, cc = lin & 7;
      int lc = cc ^ (row & 7);
      gload_lds16(Wb + (size_t)row*DH + kb + lc*8, &Bb[(size_t)chunk*64*8]);
    }
    __syncthreads();
    #pragma unroll
    for (int kk=0;kk<2;kk++){
      short8 af[2], bfr[4];
      #pragma unroll
      for (int m=0;m<2;m++){
        int row = m*16 + (lane & 15);
        int phys = (kk*4 + (lane >> 4)) ^ (row & 7);
        af[m] = *(const short8*)&Ab[row*64 + phys*8];
      }
      #pragma unroll
      for (int n=0;n<4;n++){
        int row = w*64 + n*16 + (lane & 15);
        int phys = (kk*4 + (lane >> 4)) ^ (row & 7);
        bfr[n] = *(const short8*)&Bb[row*64 + phys*8];
      }
      #pragma unroll
      for (int m=0;m<2;m++)
        #pragma unroll
        for (int n=0;n<4;n++)
          acc[m][n] = __builtin_amdgcn_mfma_f32_16x16x32_bf16(af[m], bfr[n], acc[m][n], 0,0,0);
    }
    __syncthreads();
  }
  int qr = lane >> 4, c15 = lane & 15;
  float bv[4];
  #pragma unroll
  for (int n=0;n<4;n++) bv[n] = bias[w*64 + n*16 + c15];
  #pragma unroll
  for (int m=0;m<2;m++){
    #pragma unroll
    for (int r=0;r<4;r++){
      float s = 0.f;
      #pragma unroll
      for (int n=0;n<4;n++){
        float v = acc[m][n][r] + bv[n];
        acc[m][n][r] = v;
        s += v*v;
      }
      #pragma unroll
      for (int msk=8; msk>=1; msk>>=1) s += __shfl_xor(s, msk);
      if (c15 == 0) sq[w][m*16 + qr*4 + r] = s;
    }
  }
  __syncthreads();
  if (tid < 32){
    float s = sq[0][tid] + sq[1][tid] + sq[2][tid] + sq[3][tid];
    inv_s[tid] = 1.0f / fmaxf(sqrtf(s), 1e-8f);
  }
  __syncthreads();
  #pragma unroll
  for (int m=0;m<2;m++){
    #pragma unroll
    for (int r=0;r<4;r++){
      int row = m*16 + qr*4 + r;
      float iv = inv_s[row];
      #pragma unroll
      for (int n=0;n<4;n++){
        int col = w*64 + n*16 + c15;
        enb[(size_t)(rb+row)*DE + col] = bf16b(acc[m][n][r] * iv);
      }
    }
  }
}

// ---------------- N pass, SYMMETRIC upper triangle ----------------
// block (bi,bj) with bj>=bi: S-tile 128x128; masked exp used for BOTH
// row-reduce (-> slot bj, rows of bi) and col-reduce (-> slot bi, rows of bj).
__global__ __launch_bounds__(256) void npass_kernel(const ushort* __restrict__ enb,
    const int* __restrict__ labels, float* __restrict__ N_part){
  int bi = blockIdx.x, bj = blockIdx.y;
  if (bj < bi) return;
  __shared__ ushort Ab[128*64];
  __shared__ ushort Bb[128*64];
  __shared__ float nredA[2][128];
  __shared__ float nredB[2][128];
  int tid = threadIdx.x, lane = tid & 63, w = tid >> 6;
  int wr = w >> 1, wc = w & 1;
  int rb = bi * 128;
  int cb = bj * 128;
  f32x4 acc[4][4] = {};
  for (int kb = 0; kb < DE; kb += 64){
    #pragma unroll
    for (int q=0;q<4;q++){
      int chunk = q*4 + w;
      int lin = chunk*64 + lane;
      int row = lin >> 3, cc = lin & 7;
      int lc = cc ^ (row & 7);
      gload_lds16(enb + (size_t)(rb + row)*DE + kb + lc*8, &Ab[(size_t)chunk*64*8]);
      gload_lds16(enb + (size_t)(cb + row)*DE + kb + lc*8, &Bb[(size_t)chunk*64*8]);
    }
    __syncthreads();
    #pragma unroll
    for (int kk=0;kk<2;kk++){
      short8 af[4], bfr[4];
      #pragma unroll
      for (int m=0;m<4;m++){
        int row = wr*64 + m*16 + (lane & 15);
        int phys = (kk*4 + (lane >> 4)) ^ (row & 7);
        af[m] = *(const short8*)&Ab[row*64 + phys*8];
      }
      #pragma unroll
      for (int n=0;n<4;n++){
        int row = wc*64 + n*16 + (lane & 15);
        int phys = (kk*4 + (lane >> 4)) ^ (row & 7);
        bfr[n] = *(const short8*)&Bb[row*64 + phys*8];
      }
      #pragma unroll
      for (int m=0;m<4;m++)
        #pragma unroll
        for (int n=0;n<4;n++)
          acc[m][n] = __builtin_amdgcn_mfma_f32_16x16x32_bf16(af[m], bfr[n], acc[m][n], 0,0,0);
    }
    __syncthreads();
  }
  int qr = lane >> 4, c15 = lane & 15;
  int cl[4];
  #pragma unroll
  for (int n=0;n<4;n++) cl[n] = labels[cb + wc*64 + n*16 + c15];
  float scol[4] = {0.f,0.f,0.f,0.f};
  #pragma unroll
  for (int m=0;m<4;m++){
    #pragma unroll
    for (int r=0;r<4;r++){
      int rlab = labels[rb + wr*64 + m*16 + qr*4 + r];
      float srow = 0.f;
      #pragma unroll
      for (int n=0;n<4;n++){
        float e = __expf(acc[m][n][r]);
        e = (cl[n] != rlab) ? e : 0.f;
        srow += e;
        scol[n] += e;
      }
      #pragma unroll
      for (int msk=8; msk>=1; msk>>=1) srow += __shfl_xor(srow, msk);
      if (c15 == 0) nredA[wc][wr*64 + m*16 + qr*4 + r] = srow;
    }
  }
  #pragma unroll
  for (int n=0;n<4;n++){
    scol[n] += __shfl_xor(scol[n], 16);
    scol[n] += __shfl_xor(scol[n], 32);
  }
  if (qr == 0){
    #pragma unroll
    for (int n=0;n<4;n++) nredB[wr][wc*64 + n*16 + c15] = scol[n];
  }
  __syncthreads();
  if (tid < 128){
    N_part[(size_t)bj*BS + rb + tid] = nredA[0][tid] + nredA[1][tid];
    if (bi != bj)
      N_part[(size_t)bi*BS + cb + tid] = nredB[0][tid] + nredB[1][tid];
  }
}

// ---------------- fused C-pass: pos, rowsum, T/G column partials (MFMA) ----------------
__global__ __launch_bounds__(256) void c2_kernel(const ushort* __restrict__ enb,
    const ushort* __restrict__ lnb, const int* __restrict__ labels,
    float* __restrict__ pos, float* __restrict__ rowsum,
    float* __restrict__ T_part, float* __restrict__ G_part){
  __shared__ ushort Ab[64*64];
  __shared__ ushort Bb[64*64];
  __shared__ float TpS[4][64];
  __shared__ float GpS[4][64];
  int tid = threadIdx.x, lane = tid & 63, w = tid >> 6;
  int qr = lane >> 4, c15 = lane & 15;
  int rb = blockIdx.x * 64;
  f32x4 acc[4] = {};
  for (int kb = 0; kb < DE; kb += 64){
    #pragma unroll
    for (int q=0;q<2;q++){
      int chunk = q*4 + w;
      int lin = chunk*64 + lane;
      int row = lin >> 3, cc = lin & 7;
      int lc = cc ^ (row & 7);
      gload_lds16(enb + (size_t)(rb+row)*DE + kb + lc*8, &Ab[(size_t)chunk*64*8]);
    }
    #pragma unroll
    for (int q=0;q<2;q++){
      int chunk = q*4 + w;
      int lin = chunk*64 + lane;
      int row = lin >> 3, cc = lin & 7;
      int lc = cc ^ (row & 7);
      gload_lds16(lnb + (size_t)row*DE + kb + lc*8, &Bb[(size_t)chunk*64*8]);
    }
    __syncthreads();
    #pragma unroll
    for (int kk=0;kk<2;kk++){
      int arow = w*16 + (lane & 15);
      int aphys = (kk*4 + (lane >> 4)) ^ (arow & 7);
      short8 af = *(const short8*)&Ab[arow*64 + aphys*8];
      #pragma unroll
      for (int ni=0;ni<4;ni++){
        int brow = ni*16 + (lane & 15);
        int bphys = (kk*4 + (lane >> 4)) ^ (brow & 7);
        short8 bfr = *(const short8*)&Bb[brow*64 + bphys*8];
        acc[ni] = __builtin_amdgcn_mfma_f32_16x16x32_bf16(af, bfr, acc[ni], 0,0,0);
      }
    }
    __syncthreads();
  }
  int yr[4];
  #pragma unroll
  for (int r=0;r<4;r++) yr[r] = labels[rb + w*16 + qr*4 + r];
  float e[4][4];
  #pragma unroll
  for (int ni=0;ni<4;ni++)
    #pragma unroll
    for (int r=0;r<4;r++) e[ni][r] = __expf(acc[ni][r]);
  #pragma unroll
  for (int r=0;r<4;r++){
    float rs = e[0][r]+e[1][r]+e[2][r]+e[3][r];
    float ps = 0.f;
    #pragma unroll
    for (int ni=0;ni<4;ni++) if (ni*16 + c15 == yr[r]) ps = acc[ni][r];
    #pragma unroll
    for (int msk=8; msk>=1; msk>>=1){ rs += __shfl_xor(rs, msk); ps += __shfl_xor(ps, msk); }
    if (c15 == 0){
      int grow = rb + w*16 + qr*4 + r;
      rowsum[grow] = rs;
      pos[grow] = ps;
    }
  }
  #pragma unroll
  for (int ni=0;ni<4;ni++){
    int col = ni*16 + c15;
    float t = 0.f, g = 0.f;
    #pragma unroll
    for (int r=0;r<4;r++){
      t += e[ni][r];
      if (col == yr[r]) g += e[ni][r];
    }
    t += __shfl_xor(t, 16); t += __shfl_xor(t, 32);
    g += __shfl_xor(g, 16); g += __shfl_xor(g, 32);
    if (qr == 0){ TpS[w][col] = t; GpS[w][col] = g; }
  }
  __syncthreads();
  if (tid < 64){
    T_part[(size_t)blockIdx.x*64 + tid] = TpS[0][tid]+TpS[1][tid]+TpS[2][tid]+TpS[3][tid];
    G_part[(size_t)blockIdx.x*64 + tid] = GpS[0][tid]+GpS[1][tid]+GpS[2][tid]+GpS[3][tid];
  }
}

__global__ void reduceN_kernel(const float* __restrict__ N_part, float* __restrict__ Nrow){
  int i = blockIdx.x*256 + threadIdx.x;
  float s = 0.f;
  #pragma unroll
  for (int c=0;c<64;c++) s += N_part[(size_t)c*BS + i];
  Nrow[i] = s;
}

// ---------------- same-label pairs via gathered MFMA group-GEMM ----------------
__global__ __launch_bounds__(256) void pairs_kernel(const ushort* __restrict__ enb,
    const int* __restrict__ cnt, const int* __restrict__ offs,
    const int* __restrict__ groups, const float* __restrict__ Nrow,
    float* __restrict__ pairp){
  __shared__ ushort Ab[64*64];
  __shared__ ushort Bb[256*64];
  __shared__ int aidx[64];
  __shared__ int gidx[256];
  __shared__ float red[256];
  int l = blockIdx.x, rt = blockIdx.y;
  int m = cnt[l], off = offs[l];
  int tid = threadIdx.x, lane = tid & 63, w = tid >> 6;
  int qr = lane >> 4, c15 = lane & 15;
  float sum = 0.f;
  for (int ra = rt*64; ra < m; ra += 256){
    __syncthreads();
    if (tid < 64){ int a = ra + tid; aidx[tid] = groups[off + (a < m ? a : 0)]; }
    for (int cb2 = 0; cb2 < m; cb2 += 256){
      __syncthreads();
      { int b = cb2 + tid; gidx[tid] = groups[off + (b < m ? b : 0)]; }
      __syncthreads();
      f32x4 acc[4][4] = {};
      for (int kb = 0; kb < DE; kb += 64){
        #pragma unroll
        for (int q=0;q<2;q++){
          int chunk = q*4 + w;
          int lin = chunk*64 + lane;
          int row = lin >> 3, cc = lin & 7;
          int lc = cc ^ (row & 7);
          gload_lds16(enb + (size_t)aidx[row]*DE + kb + lc*8, &Ab[(size_t)chunk*64*8]);
        }
        #pragma unroll
        for (int q=0;q<8;q++){
          int chunk = q*4 + w;
          int lin = chunk*64 + lane;
          int row = lin >> 3, cc = lin & 7;
          int lc = cc ^ (row & 7);
          gload_lds16(enb + (size_t)gidx[row]*DE + kb + lc*8, &Bb[(size_t)chunk*64*8]);
        }
        __syncthreads();
        #pragma unroll
        for (int kk=0;kk<2;kk++){
          short8 af[4], bfr[4];
          #pragma unroll
          for (int mi=0;mi<4;mi++){
            int row = mi*16 + (lane & 15);
            int phys = (kk*4 + (lane >> 4)) ^ (row & 7);
            af[mi] = *(const short8*)&Ab[row*64 + phys*8];
          }
          #pragma unroll
          for (int ni=0;ni<4;ni++){
            int row = w*64 + ni*16 + (lane & 15);
            int phys = (kk*4 + (lane >> 4)) ^ (row & 7);
            bfr[ni] = *(const short8*)&Bb[row*64 + phys*8];
          }
          #pragma unroll
          for (int mi=0;mi<4;mi++)
            #pragma unroll
            for (int ni=0;ni<4;ni++)
              acc[mi][ni] = __builtin_amdgcn_mfma_f32_16x16x32_bf16(af[mi], bfr[ni], acc[mi][ni], 0,0,0);
        }
        __syncthreads();
      }
      #pragma unroll
      for (int mi=0;mi<4;mi++){
        #pragma unroll
        for (int r=0;r<4;r++){
          int arel = mi*16 + qr*4 + r;
          int a = ra + arel;
          if (a < m){
            float Ni = Nrow[aidx[arel]];
            #pragma unroll
            for (int ni=0;ni<4;ni++){
              int b = cb2 + w*64 + ni*16 + c15;
              if (b < m && b != a){
                float s = acc[mi][ni][r];
                sum += -s + __logf(Ni + __expf(s));
              }
            }
          }
        }
      }
    }
  }
  red[tid] = sum;
  __syncthreads();
  for (int s=128;s>0;s>>=1){ if (tid<s) red[tid]+=red[tid+s]; __syncthreads(); }
  if (tid==0) pairp[l*4 + rt] = red[0];
}

// ---------------- final scalar assembly (f32 math, f64 accumulation) ----------------
__global__ void finalize_kernel(const int* __restrict__ labels, const int* __restrict__ cnt,
    const float* __restrict__ Nrow, const float* __restrict__ pos,
    const float* __restrict__ rowsum, const float* __restrict__ T_part,
    const float* __restrict__ G_part, const float* __restrict__ pairp,
    float* __restrict__ out){
  __shared__ double red[3*256];
  __shared__ float TGf[64];
  int t = threadIdx.x;
  if (t < 64){
    float ts = 0.f, gs = 0.f;
    for (int b=0;b<128;b++){ ts += T_part[b*64 + t]; gs += G_part[b*64 + t]; }
    TGf[t] = ts - gs;
  }
  __syncthreads();
  double a=0.0, p1=0.0, p2=0.0;
  for (int i=t; i<BS; i+=256){
    int y = labels[i];
    float Ni = Nrow[i];
    a += (double)((float)(BS - cnt[y]) * __logf(Ni + 1.0f));
    float ps = pos[i];
    p1 += (double)(-ps + __logf(rowsum[i]));
    p2 += (double)(-ps + __logf(TGf[y] + __expf(ps)));
  }
  red[t]=a; red[256+t]=p1; red[512+t]=p2;
  __syncthreads();
  for (int s=128;s>0;s>>=1){
    if (t<s){ red[t]+=red[t+s]; red[256+t]+=red[256+t+s]; red[512+t]+=red[512+t+s]; }
    __syncthreads();
  }
  if (t==0){
    double pair = 0.0;
    for (int l=0;l<256;l++) pair += (double)pairp[l];
    double inter = (red[0] + pair) / ((double)BS * (double)BS);
    double proto = (red[256] + red[512]) / (double)BS;
    out[0] = (float)(0.5*inter + 0.5*proto);
  }
}

extern "C" void kernel_launch(void* const* d_in, const int* in_sizes, int n_in,
                              void* d_out, int out_size, void* d_ws, size_t ws_size,
                              hipStream_t stream){
  const float* mask  = (const float*)d_in[0];
  const float* W     = (const float*)d_in[1];
  const float* bias  = (const float*)d_in[2];
  const float* lemb  = (const float*)d_in[3];
  const int*   labels= (const int*)d_in[4];
  float* out = (float*)d_out;

  // workspace layout (~7 MB)
  ushort* enb    = (ushort*)d_ws;                   // 8192*256 bf16 (4MB)
  ushort* Wb     = enb + (size_t)BS*DE;             // 256*1024 bf16 (512KB)
  ushort* lnb    = Wb + (size_t)DE*DH;              // 64*256 bf16 (32KB)
  float*  N_part = (float*)(lnb + (size_t)NL*DE);   // 64*8192 (2MB)
  float*  Nrow   = N_part + (size_t)64*BS;          // 8192
  float*  pos    = Nrow + BS;                       // 8192
  float*  rowsum = pos + BS;                        // 8192
  float*  T_part = rowsum + BS;                     // 128*64
  float*  G_part = T_part + 128*64;                 // 128*64
  float*  pairp  = G_part + 128*64;                 // 256
  int* cnt    = (int*)(pairp + 256);                // 64
  int* offs   = cnt + NL;                           // 65 (pad 68)
  int* groups = offs + 68;                          // 8192

  hipLaunchKernelGGL(prep_kernel,     dim3(193), dim3(256), 0, stream, W, Wb, lemb, lnb, labels, cnt, offs, groups);
  hipLaunchKernelGGL(emb_kernel,      dim3(BS/32), dim3(256), 0, stream, mask, Wb, bias, enb);
  hipLaunchKernelGGL(npass_kernel,    dim3(BS/128, BS/128), dim3(256), 0, stream, enb, labels, N_part);
  hipLaunchKernelGGL(c2_kernel,       dim3(BS/64), dim3(256), 0, stream, enb, lnb, labels, pos, rowsum, T_part, G_part);
  hipLaunchKernelGGL(reduceN_kernel,  dim3(BS/256), dim3(256), 0, stream, N_part, Nrow);
  hipLaunchKernelGGL(pairs_kernel,    dim3(NL, 4), dim3(256), 0, stream, enb, cnt, offs, groups, Nrow, pairp);
  hipLaunchKernelGGL(finalize_kernel, dim3(1), dim3(256), 0, stream, labels, cnt, Nrow, pos, rowsum, T_part, G_part, pairp, out);
}